// Round 3
// baseline (612.860 us; speedup 1.0000x reference)
//
#include <hip/hip_runtime.h>
#include <hip/hip_bf16.h>

typedef __bf16 bf16;
typedef __bf16 bf16x4 __attribute__((ext_vector_type(4)));
typedef __bf16 bf16x8 __attribute__((ext_vector_type(8)));
typedef float f32x4 __attribute__((ext_vector_type(4)));

#define MFMA16(a, b, c) __builtin_amdgcn_mfma_f32_16x16x32_bf16((a), (b), (c), 0, 0, 0)

#if __has_builtin(__builtin_amdgcn_exp2f)
#define EXP2(x) __builtin_amdgcn_exp2f(x)
#else
#define EXP2(x) exp2f(x)
#endif

constexpr int EMBED = 1024;
constexpr int HEADS = 16;
constexpr int HD = 64;
constexpr int SEQ = 2048;
constexpr int NB = 4;
constexpr int SXTP = 76;   // proj V-transpose stride
constexpr int SPD = 72;    // flash sP stride (rows 16B-aligned, 2-way banks)
constexpr int WO_N = EMBED * EMBED;

// softmax scale 1/sqrt(1024) folded with log2(e); folded into Wq conversion
#define QSCALE 0.04508422082f

// ---------------- all weights fp32 -> bf16 (Q scale folded into Wq) --------
__global__ __launch_bounds__(256) void convert_weights(
    const float* __restrict__ Wo, const float* __restrict__ Wq,
    const float* __restrict__ Wk, const float* __restrict__ Wv,
    bf16* __restrict__ Wob, bf16* __restrict__ Wqb,
    bf16* __restrict__ Wkb, bf16* __restrict__ Wvb) {
    int gid = blockIdx.x * 256 + threadIdx.x;
    int base = gid * 8;
    const float* src;
    bf16* dst;
    float sc = 1.0f;
    int off;
    if (base < WO_N) {
        src = Wo; dst = Wob; off = base;
    } else {
        int j = base - WO_N;      // 0..12287
        int w = j >> 12;          // which small weight
        off = j & 4095;
        src = (w == 0) ? Wq : (w == 1) ? Wk : Wv;
        dst = (w == 0) ? Wqb : (w == 1) ? Wkb : Wvb;
        if (w == 0) sc = QSCALE;
    }
    float4 a = *(const float4*)(src + off);
    float4 b = *(const float4*)(src + off + 4);
    bf16x8 o;
    o[0] = (bf16)(a.x * sc); o[1] = (bf16)(a.y * sc);
    o[2] = (bf16)(a.z * sc); o[3] = (bf16)(a.w * sc);
    o[4] = (bf16)(b.x * sc); o[5] = (bf16)(b.y * sc);
    o[6] = (bf16)(b.z * sc); o[7] = (bf16)(b.w * sc);
    *(bf16x8*)(dst + off) = o;
}

// ---------------- QKV per-head projections (no staging LDS) ----------------
// A-frags converted fp32->bf16 in-register straight from global; B-frags are
// pre-converted bf16 weights (L1-hot). LDS only for the V-transpose.
__global__ __launch_bounds__(256) void proj_kernel(
    const float* __restrict__ Vx, const float* __restrict__ Kx, const float* __restrict__ Qx,
    const bf16* __restrict__ Wqb, const bf16* __restrict__ Wkb, const bf16* __restrict__ Wvb,
    bf16* __restrict__ Vt, bf16* __restrict__ Kp, bf16* __restrict__ Qp) {
    __shared__ __align__(16) bf16 sXT[64 * SXTP];
    int t = threadIdx.x, lane = t & 63, wq = t >> 6;
    int m = lane & 15, q8 = lane >> 4;
    int rowbase = blockIdx.x * 64;
    int Arow = rowbase + wq * 16 + m;
    const float* Xs[3] = {Qx, Kx, Vx};
    const bf16* Ws[3] = {Wqb, Wkb, Wvb};
    f32x4 z = {0.f, 0.f, 0.f, 0.f};

    for (int ts = 0; ts < 3; ts++) {
        // A frags: 8 consecutive fp32 per c-half, converted in-register
        bf16x8 af[2];
        for (int c = 0; c < 2; c++) {
            const float* s = Xs[ts] + (size_t)Arow * 64 + c * 32 + q8 * 8;
            float4 x0 = *(const float4*)s;
            float4 x1 = *(const float4*)(s + 4);
            bf16x8 a;
            a[0] = (bf16)x0.x; a[1] = (bf16)x0.y; a[2] = (bf16)x0.z; a[3] = (bf16)x0.w;
            a[4] = (bf16)x1.x; a[5] = (bf16)x1.y; a[6] = (bf16)x1.z; a[7] = (bf16)x1.w;
            af[c] = a;
        }
        // B frags (8 KB per weight, L1-resident after first block on CU)
        bf16x8 bfr[4][2];
        for (int nt = 0; nt < 4; nt++)
            for (int c = 0; c < 2; c++)
                bfr[nt][c] = *(const bf16x8*)(Ws[ts] + (nt * 16 + m) * 64 + c * 32 + q8 * 8);
        f32x4 acc[4] = {z, z, z, z};
        for (int c = 0; c < 2; c++)
            for (int nt = 0; nt < 4; nt++)
                acc[nt] = MFMA16(af[c], bfr[nt][c], acc[nt]);

        if (ts < 2) {
            bf16* dst = (ts == 0) ? Qp : Kp;
            for (int nt = 0; nt < 4; nt++) {
                int e = nt * 16 + m;
                for (int jr = 0; jr < 4; jr++) {
                    int R = rowbase + wq * 16 + q8 * 4 + jr;
                    int h = R & 15, l = (R >> 4) & 2047, n = R >> 15;
                    dst[((size_t)(n * HEADS + h) * SEQ + l) * HD + e] = (bf16)acc[nt][jr];
                }
            }
        } else {
            // V: acc -> sXT[e][r], then gather-transpose to Vt[n,h,d,l] (b64 stores)
            for (int nt = 0; nt < 4; nt++) {
                bf16x4 pv;
                pv[0] = (bf16)acc[nt][0]; pv[1] = (bf16)acc[nt][1];
                pv[2] = (bf16)acc[nt][2]; pv[3] = (bf16)acc[nt][3];
                *(bf16x4*)&sXT[(nt * 16 + m) * SXTP + wq * 16 + q8 * 4] = pv;
            }
            __syncthreads();
            int n = rowbase >> 15, l0 = (rowbase >> 4) & 2047;
            for (int i = t; i < 1024; i += 256) {
                int e = i & 63, hh = i >> 6;
                bf16x4 pv;
                pv[0] = sXT[e * SXTP + 0 * 16 + hh];
                pv[1] = sXT[e * SXTP + 1 * 16 + hh];
                pv[2] = sXT[e * SXTP + 2 * 16 + hh];
                pv[3] = sXT[e * SXTP + 3 * 16 + hh];
                *(bf16x4*)(Vt + ((size_t)(n * HEADS + hh) * HD + e) * SEQ + l0) = pv;
            }
        }
    }
}

// ---------------- flash attention: prefetched barrier-free K-loop ----------
// Block = 4 waves x 32 q = 128 q; grid (nh, qt) for XCD L2 locality.
// K prefetched one full iteration ahead (kfA/kfB alternating, no reg copies);
// V issued at iter top (QK+exp cover). No-max softmax, exp2 via pre-scaled Q.
__global__ __launch_bounds__(256, 4) void flash_kernel(
    const bf16* __restrict__ Qp, const bf16* __restrict__ Kp, const bf16* __restrict__ Vt,
    bf16* __restrict__ O) {
    int nh = blockIdx.x, qt = blockIdx.y;
    int n = nh >> 4, h = nh & 15;
    int t = threadIdx.x, lane = t & 63, wq = t >> 6;
    int m = lane & 15, q8 = lane >> 4;
    __shared__ __align__(16) bf16 sP[4][32 * SPD];
    __shared__ float sL[4][32];
    size_t nhs = (size_t)nh;
    int qb = qt * 128 + wq * 32;
    const bf16* Qb = Qp + (nhs * SEQ + qb) * HD;
    const bf16* Kb = Kp + nhs * SEQ * HD;
    const bf16* Vb = Vt + nhs * (size_t)HD * SEQ;
    bf16* sPw = sP[wq];

    bf16x8 qf[2][2];
    for (int ntq = 0; ntq < 2; ntq++)
        for (int c = 0; c < 2; c++)
            qf[ntq][c] = *(const bf16x8*)(Qb + (ntq * 16 + m) * HD + c * 32 + q8 * 8);

    f32x4 z = {0.f, 0.f, 0.f, 0.f};
    f32x4 accO[2][4];
    for (int a = 0; a < 2; a++)
        for (int b = 0; b < 4; b++) accO[a][b] = z;
    f32x4 lsumv[2] = {z, z};

    bf16x8 kfA[4][2], kfB[4][2];
    for (int kt = 0; kt < 4; kt++)
        for (int c = 0; c < 2; c++)
            kfA[kt][c] = *(const bf16x8*)(Kb + (size_t)(kt * 16 + m) * HD + c * 32 + q8 * 8);

    auto half = [&](int kcur, bf16x8 (&kf)[4][2], bf16x8 (&kfn)[4][2], int knext) {
        // V for this tile: issued first -> PV's wait leaves K-prefetch in flight
        bf16x8 vf[4][2];
        for (int dt = 0; dt < 4; dt++)
            for (int c = 0; c < 2; c++)
                vf[dt][c] = *(const bf16x8*)(Vb + (size_t)(dt * 16 + m) * SEQ + kcur + c * 32 + q8 * 8);
        // K prefetch for NEXT tile (full-iteration cover)
        for (int kt = 0; kt < 4; kt++)
            for (int c = 0; c < 2; c++)
                kfn[kt][c] = *(const bf16x8*)(Kb + (size_t)(knext + kt * 16 + m) * HD + c * 32 + q8 * 8);
        // S^T = K Q^T
        f32x4 st[4][2];
        for (int kt = 0; kt < 4; kt++)
            for (int ntq = 0; ntq < 2; ntq++) st[kt][ntq] = z;
        for (int c = 0; c < 2; c++)
            for (int kt = 0; kt < 4; kt++)
                for (int ntq = 0; ntq < 2; ntq++)
                    st[kt][ntq] = MFMA16(kf[kt][c], qf[ntq][c], st[kt][ntq]);
        // p = exp2(s), lane-local row sums, b64-packed P -> per-wave LDS
        for (int kt = 0; kt < 4; kt++)
            for (int ntq = 0; ntq < 2; ntq++) {
                f32x4 p;
                p[0] = EXP2(st[kt][ntq][0]); p[1] = EXP2(st[kt][ntq][1]);
                p[2] = EXP2(st[kt][ntq][2]); p[3] = EXP2(st[kt][ntq][3]);
                lsumv[ntq] += p;
                bf16x4 pb;
                pb[0] = (bf16)p[0]; pb[1] = (bf16)p[1]; pb[2] = (bf16)p[2]; pb[3] = (bf16)p[3];
                *(bf16x4*)(sPw + (ntq * 16 + m) * SPD + kt * 16 + q8 * 4) = pb;
            }
        // O += P V (same-wave LDS round-trip, no barrier)
        bf16x8 pf[2][2];
        for (int mtq = 0; mtq < 2; mtq++)
            for (int c = 0; c < 2; c++)
                pf[mtq][c] = *(const bf16x8*)(sPw + (mtq * 16 + m) * SPD + c * 32 + q8 * 8);
        for (int c = 0; c < 2; c++)
            for (int mtq = 0; mtq < 2; mtq++)
                for (int dt = 0; dt < 4; dt++)
                    accO[mtq][dt] = MFMA16(pf[mtq][c], vf[dt][c], accO[mtq][dt]);
    };

    for (int kb = 0; kb < SEQ; kb += 128) {
        half(kb, kfA, kfB, kb + 64);
        half(kb + 64, kfB, kfA, (kb + 128) & (SEQ - 1));  // tail wraps to 0 (harmless)
    }

    for (int ntq = 0; ntq < 2; ntq++) {
        float s = lsumv[ntq][0] + lsumv[ntq][1] + lsumv[ntq][2] + lsumv[ntq][3];
        s += __shfl_xor(s, 16);
        s += __shfl_xor(s, 32);
        sL[wq][ntq * 16 + m] = s;
    }
    f32x4 linv[2];
    for (int mtq = 0; mtq < 2; mtq++)
        linv[mtq] = *(f32x4*)&sL[wq][mtq * 16 + q8 * 4];
    for (int mtq = 0; mtq < 2; mtq++)
        for (int j = 0; j < 4; j++) {
            float iv = 1.0f / linv[mtq][j];
            int q = qb + mtq * 16 + q8 * 4 + j;
            size_t ro = ((size_t)n * SEQ + q) * EMBED + h * HD;
            for (int dt = 0; dt < 4; dt++)
                O[ro + dt * 16 + m] = (bf16)(accO[mtq][dt][j] * iv);
        }
}

// ---------------- output projection with A/B-parity register prefetch ------
__global__ __launch_bounds__(256, 4) void outproj_kernel(
    const bf16* __restrict__ O, const bf16* __restrict__ Wob,
    const float* __restrict__ bo, float* __restrict__ out) {
    int et = blockIdx.x, qt = blockIdx.y;
    int t = threadIdx.x, lane = t & 63, wq = t >> 6;
    int m = lane & 15, q8 = lane >> 4;
    int qb = qt * 128 + wq * 32;
    const bf16* Ob = O + (size_t)qb * EMBED;
    const bf16* Wb = Wob + (size_t)et * 64 * EMBED;
    f32x4 z = {0.f, 0.f, 0.f, 0.f};
    f32x4 acc[2][4];
    for (int a = 0; a < 2; a++)
        for (int b = 0; b < 4; b++) acc[a][b] = z;

    bf16x8 afA[2], bfA[4], afB[2], bfB[4];
    auto loadA = [&](int kk) {
        for (int mt = 0; mt < 2; mt++)
            afA[mt] = *(const bf16x8*)(Ob + (size_t)(mt * 16 + m) * EMBED + kk + q8 * 8);
        for (int nt = 0; nt < 4; nt++)
            bfA[nt] = *(const bf16x8*)(Wb + (size_t)(nt * 16 + m) * EMBED + kk + q8 * 8);
    };
    auto loadB = [&](int kk) {
        for (int mt = 0; mt < 2; mt++)
            afB[mt] = *(const bf16x8*)(Ob + (size_t)(mt * 16 + m) * EMBED + kk + q8 * 8);
        for (int nt = 0; nt < 4; nt++)
            bfB[nt] = *(const bf16x8*)(Wb + (size_t)(nt * 16 + m) * EMBED + kk + q8 * 8);
    };
    loadA(0);
    loadB(32);
    for (int kk = 0; kk < EMBED; kk += 64) {
        for (int mt = 0; mt < 2; mt++)
            for (int nt = 0; nt < 4; nt++)
                acc[mt][nt] = MFMA16(afA[mt], bfA[nt], acc[mt][nt]);
        loadA((kk + 64) & (EMBED - 1));  // tail wraps (harmless)
        for (int mt = 0; mt < 2; mt++)
            for (int nt = 0; nt < 4; nt++)
                acc[mt][nt] = MFMA16(afB[mt], bfB[nt], acc[mt][nt]);
        loadB((kk + 96) & (EMBED - 1));
    }
    for (int nt = 0; nt < 4; nt++) {
        int col = et * 64 + nt * 16 + m;
        float bias = bo[col];
        for (int mt = 0; mt < 2; mt++)
            for (int j = 0; j < 4; j++) {
                int q = qb + mt * 16 + q8 * 4 + j;
                out[(size_t)q * EMBED + col] = acc[mt][nt][j] + bias;
            }
    }
}

extern "C" void kernel_launch(void* const* d_in, const int* in_sizes, int n_in,
                              void* d_out, int out_size, void* d_ws, size_t ws_size,
                              hipStream_t stream) {
    const float* values = (const float*)d_in[0];
    const float* keys   = (const float*)d_in[1];
    const float* query  = (const float*)d_in[2];
    const float* Wv     = (const float*)d_in[3];
    const float* Wk     = (const float*)d_in[4];
    const float* Wq     = (const float*)d_in[5];
    const float* Wo     = (const float*)d_in[6];
    const float* bo     = (const float*)d_in[7];
    float* out = (float*)d_out;

    char* ws = (char*)d_ws;
    bf16* Qp  = (bf16*)(ws);
    bf16* Kp  = (bf16*)(ws + (size_t)(16 << 20));
    bf16* Vt  = (bf16*)(ws + (size_t)(32 << 20));
    bf16* O   = (bf16*)(ws + (size_t)(48 << 20));
    bf16* Wob = (bf16*)(ws + (size_t)(64 << 20));
    bf16* Wqb = (bf16*)(ws + (size_t)(66 << 20));
    bf16* Wkb = (bf16*)(ws + (size_t)(66 << 20) + 8192);
    bf16* Wvb = (bf16*)(ws + (size_t)(66 << 20) + 16384);

    hipLaunchKernelGGL(convert_weights, dim3(518), dim3(256), 0, stream,
                       Wo, Wq, Wk, Wv, Wob, Wqb, Wkb, Wvb);
    hipLaunchKernelGGL(proj_kernel, dim3(2048), dim3(256), 0, stream,
                       values, keys, query, Wqb, Wkb, Wvb, Vt, Kp, Qp);
    hipLaunchKernelGGL(flash_kernel, dim3(64, 16), dim3(256), 0, stream, Qp, Kp, Vt, O);
    hipLaunchKernelGGL(outproj_kernel, dim3(16, 64), dim3(256), 0, stream, O, Wob, bo, out);
}

// Round 4
// 366.666 us; speedup vs baseline: 1.6714x; 1.6714x over previous
//
#include <hip/hip_runtime.h>
#include <hip/hip_bf16.h>

typedef __bf16 bf16;
typedef __bf16 bf16x4 __attribute__((ext_vector_type(4)));
typedef __bf16 bf16x8 __attribute__((ext_vector_type(8)));
typedef float f32x4 __attribute__((ext_vector_type(4)));

#define MFMA16(a, b, c) __builtin_amdgcn_mfma_f32_16x16x32_bf16((a), (b), (c), 0, 0, 0)

#if __has_builtin(__builtin_amdgcn_exp2f)
#define EXP2(x) __builtin_amdgcn_exp2f(x)
#else
#define EXP2(x) exp2f(x)
#endif

constexpr int EMBED = 1024;
constexpr int HEADS = 16;
constexpr int HD = 64;
constexpr int SEQ = 2048;
constexpr int LDSP = 72;   // padded LDS stride: 144 B rows (16B-aligned, 2-way banks = free)
constexpr int SXTP = 76;   // proj V-transpose stride
constexpr int WO_N = EMBED * EMBED;

// softmax scale 1/sqrt(1024) folded with log2(e); folded into Wq conversion
#define QSCALE 0.04508422082f

// ---------------- all weights fp32 -> bf16 (Q scale folded into Wq) --------
__global__ __launch_bounds__(256) void convert_weights(
    const float* __restrict__ Wo, const float* __restrict__ Wq,
    const float* __restrict__ Wk, const float* __restrict__ Wv,
    bf16* __restrict__ Wob, bf16* __restrict__ Wqb,
    bf16* __restrict__ Wkb, bf16* __restrict__ Wvb) {
    int gid = blockIdx.x * 256 + threadIdx.x;
    int base = gid * 8;
    const float* src;
    bf16* dst;
    float sc = 1.0f;
    int off;
    if (base < WO_N) {
        src = Wo; dst = Wob; off = base;
    } else {
        int j = base - WO_N;
        int w = j >> 12;
        off = j & 4095;
        src = (w == 0) ? Wq : (w == 1) ? Wk : Wv;
        dst = (w == 0) ? Wqb : (w == 1) ? Wkb : Wvb;
        if (w == 0) sc = QSCALE;
    }
    float4 a = *(const float4*)(src + off);
    float4 b = *(const float4*)(src + off + 4);
    bf16x8 o;
    o[0] = (bf16)(a.x * sc); o[1] = (bf16)(a.y * sc);
    o[2] = (bf16)(a.z * sc); o[3] = (bf16)(a.w * sc);
    o[4] = (bf16)(b.x * sc); o[5] = (bf16)(b.y * sc);
    o[6] = (bf16)(b.z * sc); o[7] = (bf16)(b.w * sc);
    *(bf16x8*)(dst + off) = o;
}

// ---------------- QKV per-head projections ----------------
// A-frags converted fp32->bf16 in-register from global; B-frags are bf16
// weights (L1-hot). Q/K epilogue goes through an LDS transpose so global
// stores are coalesced 16B chunks (was: 16 scalar 2B scatter stores/lane).
__global__ __launch_bounds__(256) void proj_kernel(
    const float* __restrict__ Vx, const float* __restrict__ Kx, const float* __restrict__ Qx,
    const bf16* __restrict__ Wqb, const bf16* __restrict__ Wkb, const bf16* __restrict__ Wvb,
    bf16* __restrict__ Vt, bf16* __restrict__ Kp, bf16* __restrict__ Qp) {
    __shared__ __align__(16) bf16 sT[64 * LDSP];
    __shared__ __align__(16) bf16 sXT[64 * SXTP];
    int t = threadIdx.x, lane = t & 63, wq = t >> 6;
    int m = lane & 15, q8 = lane >> 4;
    int rowbase = blockIdx.x * 64;
    int Arow = rowbase + wq * 16 + m;
    const float* Xs[3] = {Qx, Kx, Vx};
    const bf16* Ws[3] = {Wqb, Wkb, Wvb};
    f32x4 z = {0.f, 0.f, 0.f, 0.f};

    for (int ts = 0; ts < 3; ts++) {
        bf16x8 af[2];
        for (int c = 0; c < 2; c++) {
            const float* s = Xs[ts] + (size_t)Arow * 64 + c * 32 + q8 * 8;
            float4 x0 = *(const float4*)s;
            float4 x1 = *(const float4*)(s + 4);
            bf16x8 a;
            a[0] = (bf16)x0.x; a[1] = (bf16)x0.y; a[2] = (bf16)x0.z; a[3] = (bf16)x0.w;
            a[4] = (bf16)x1.x; a[5] = (bf16)x1.y; a[6] = (bf16)x1.z; a[7] = (bf16)x1.w;
            af[c] = a;
        }
        bf16x8 bfr[4][2];
        for (int nt = 0; nt < 4; nt++)
            for (int c = 0; c < 2; c++)
                bfr[nt][c] = *(const bf16x8*)(Ws[ts] + (nt * 16 + m) * 64 + c * 32 + q8 * 8);
        f32x4 acc[4] = {z, z, z, z};
        for (int c = 0; c < 2; c++)
            for (int nt = 0; nt < 4; nt++)
                acc[nt] = MFMA16(af[c], bfr[nt][c], acc[nt]);

        if (ts < 2) {
            __syncthreads();  // prior ts's sT reads done
            for (int nt = 0; nt < 4; nt++)
                for (int jr = 0; jr < 4; jr++)
                    sT[(wq * 16 + q8 * 4 + jr) * LDSP + nt * 16 + m] = (bf16)acc[nt][jr];
            __syncthreads();
            // coalesced store: 4 threads per row, 16B chunks
            int r = t >> 2, c4 = t & 3;
            int R = rowbase + r;
            int h = R & 15, l = (R >> 4) & 2047, n = R >> 15;
            bf16* dst = ((ts == 0) ? Qp : Kp) + ((size_t)(n * HEADS + h) * SEQ + l) * HD + c4 * 16;
            bf16x8 v0 = *(const bf16x8*)&sT[r * LDSP + c4 * 16];
            bf16x8 v1 = *(const bf16x8*)&sT[r * LDSP + c4 * 16 + 8];
            *(bf16x8*)dst = v0;
            *(bf16x8*)(dst + 8) = v1;
        } else {
            // V: acc -> sXT[e][r], gather-transpose to Vt[n,h,d,l] (b64 stores)
            for (int nt = 0; nt < 4; nt++) {
                bf16x4 pv;
                pv[0] = (bf16)acc[nt][0]; pv[1] = (bf16)acc[nt][1];
                pv[2] = (bf16)acc[nt][2]; pv[3] = (bf16)acc[nt][3];
                *(bf16x4*)&sXT[(nt * 16 + m) * SXTP + wq * 16 + q8 * 4] = pv;
            }
            __syncthreads();
            int n = rowbase >> 15, l0 = (rowbase >> 4) & 2047;
            for (int i = t; i < 1024; i += 256) {
                int e = i & 63, hh = i >> 6;
                bf16x4 pv;
                pv[0] = sXT[e * SXTP + 0 * 16 + hh];
                pv[1] = sXT[e * SXTP + 1 * 16 + hh];
                pv[2] = sXT[e * SXTP + 2 * 16 + hh];
                pv[3] = sXT[e * SXTP + 3 * 16 + hh];
                *(bf16x4*)(Vt + ((size_t)(n * HEADS + hh) * HD + e) * SEQ + l0) = pv;
            }
        }
    }
}

// ---------------- flash attention: LDS-staged K/V + register prefetch ------
// Block = 4 waves x 32 q = 128 q. K/V tile (16 KB) staged in LDS once per
// block (4x less L2 traffic than per-wave frags); next tile prefetched into
// 16 VGPRs/thread right after QK, written to LDS after the read barrier.
// No-max softmax (|s| <~ 2), exp2 via pre-scaled Q; per-wave sP (no barrier).
__global__ __launch_bounds__(256) void flash_kernel(
    const bf16* __restrict__ Qp, const bf16* __restrict__ Kp, const bf16* __restrict__ Vt,
    bf16* __restrict__ O) {
    int nh = blockIdx.x, qt = blockIdx.y;   // all qt of one head -> same XCD
    int n = nh >> 4, h = nh & 15;
    int t = threadIdx.x, lane = t & 63, wq = t >> 6;
    int m = lane & 15, q8 = lane >> 4;
    __shared__ __align__(16) bf16 sK[64 * LDSP];
    __shared__ __align__(16) bf16 sV[64 * LDSP];
    __shared__ __align__(16) bf16 sP[4][32 * LDSP];
    __shared__ float sL[4][32];
    size_t nhs = (size_t)nh;
    int qb = qt * 128 + wq * 32;
    const bf16* Qb = Qp + (nhs * SEQ + qb) * HD;
    const bf16* Kb = Kp + nhs * SEQ * HD;
    const bf16* Vb = Vt + nhs * (size_t)HD * SEQ;
    bf16* sPw = sP[wq];

    // staging map: threads 0..127 -> K tile (row, half-row), 128..255 -> V tile
    bool isK = t < 128;
    int t2 = isK ? t : t - 128;
    int srow = t2 >> 1, shalf = t2 & 1;
    const bf16* sbase = isK ? (Kb + (size_t)srow * HD + shalf * 32)
                            : (Vb + (size_t)srow * SEQ + shalf * 32);
    size_t sstride = isK ? (size_t)HD : 1;  // advance per k-index
    bf16* ldst = (isK ? sK : sV) + srow * LDSP + shalf * 32;

    bf16x8 qf[2][2];
    for (int ntq = 0; ntq < 2; ntq++)
        for (int c = 0; c < 2; c++)
            qf[ntq][c] = *(const bf16x8*)(Qb + (ntq * 16 + m) * HD + c * 32 + q8 * 8);

    f32x4 z = {0.f, 0.f, 0.f, 0.f};
    f32x4 accO[2][4];
    for (int a = 0; a < 2; a++)
        for (int b = 0; b < 4; b++) accO[a][b] = z;
    f32x4 lsumv[2] = {z, z};

    bf16x8 stg[4];
    auto load_stage = [&](int kb) {
        for (int j = 0; j < 4; j++)
            stg[j] = *(const bf16x8*)(sbase + (size_t)kb * sstride + j * 8);
    };
    auto write_stage = [&]() {
        for (int j = 0; j < 4; j++)
            *(bf16x8*)(ldst + j * 8) = stg[j];
    };

    load_stage(0);
    write_stage();
    __syncthreads();

    for (int kb = 0; kb < SEQ; kb += 64) {
        // S^T = K Q^T from LDS
        bf16x8 kf[4][2];
        for (int kt = 0; kt < 4; kt++)
            for (int c = 0; c < 2; c++)
                kf[kt][c] = *(const bf16x8*)&sK[(kt * 16 + m) * LDSP + c * 32 + q8 * 8];
        f32x4 st[4][2];
        for (int kt = 0; kt < 4; kt++)
            for (int ntq = 0; ntq < 2; ntq++) st[kt][ntq] = z;
        for (int c = 0; c < 2; c++)
            for (int kt = 0; kt < 4; kt++)
                for (int ntq = 0; ntq < 2; ntq++)
                    st[kt][ntq] = MFMA16(kf[kt][c], qf[ntq][c], st[kt][ntq]);
        // prefetch next tile into regs (covered by exp + LDS + PV below)
        load_stage((kb + 64) & (SEQ - 1));
        // V frags from LDS (into regs before the overwrite barrier)
        bf16x8 vf[4][2];
        for (int dt = 0; dt < 4; dt++)
            for (int c = 0; c < 2; c++)
                vf[dt][c] = *(const bf16x8*)&sV[(dt * 16 + m) * LDSP + c * 32 + q8 * 8];
        // p = exp2(s), lane-local row sums, b64-packed P -> per-wave LDS
        for (int kt = 0; kt < 4; kt++)
            for (int ntq = 0; ntq < 2; ntq++) {
                f32x4 p;
                p[0] = EXP2(st[kt][ntq][0]); p[1] = EXP2(st[kt][ntq][1]);
                p[2] = EXP2(st[kt][ntq][2]); p[3] = EXP2(st[kt][ntq][3]);
                lsumv[ntq] += p;
                bf16x4 pb;
                pb[0] = (bf16)p[0]; pb[1] = (bf16)p[1]; pb[2] = (bf16)p[2]; pb[3] = (bf16)p[3];
                *(bf16x4*)(sPw + (ntq * 16 + m) * LDSP + kt * 16 + q8 * 4) = pb;
            }
        // O += P V (same-wave LDS round-trip for P)
        bf16x8 pf[2][2];
        for (int mtq = 0; mtq < 2; mtq++)
            for (int c = 0; c < 2; c++)
                pf[mtq][c] = *(const bf16x8*)(sPw + (mtq * 16 + m) * LDSP + c * 32 + q8 * 8);
        for (int c = 0; c < 2; c++)
            for (int mtq = 0; mtq < 2; mtq++)
                for (int dt = 0; dt < 4; dt++)
                    accO[mtq][dt] = MFMA16(pf[mtq][c], vf[dt][c], accO[mtq][dt]);
        __syncthreads();   // all waves done reading sK/sV
        write_stage();     // install tile t+1
        __syncthreads();   // tile t+1 visible
    }

    for (int ntq = 0; ntq < 2; ntq++) {
        float s = lsumv[ntq][0] + lsumv[ntq][1] + lsumv[ntq][2] + lsumv[ntq][3];
        s += __shfl_xor(s, 16);
        s += __shfl_xor(s, 32);
        sL[wq][ntq * 16 + m] = s;
    }
    f32x4 linv[2];
    for (int mtq = 0; mtq < 2; mtq++)
        linv[mtq] = *(f32x4*)&sL[wq][mtq * 16 + q8 * 4];
    for (int mtq = 0; mtq < 2; mtq++)
        for (int j = 0; j < 4; j++) {
            float iv = 1.0f / linv[mtq][j];
            int q = qb + mtq * 16 + q8 * 4 + j;
            size_t ro = ((size_t)n * SEQ + q) * EMBED + h * HD;
            for (int dt = 0; dt < 4; dt++)
                O[ro + dt * 16 + m] = (bf16)(accO[mtq][dt][j] * iv);
        }
}

// ---------------- output projection with A/B-parity register prefetch ------
__global__ __launch_bounds__(256) void outproj_kernel(
    const bf16* __restrict__ O, const bf16* __restrict__ Wob,
    const float* __restrict__ bo, float* __restrict__ out) {
    int et = blockIdx.x, qt = blockIdx.y;
    int t = threadIdx.x, lane = t & 63, wq = t >> 6;
    int m = lane & 15, q8 = lane >> 4;
    int qb = qt * 128 + wq * 32;
    const bf16* Ob = O + (size_t)qb * EMBED;
    const bf16* Wb = Wob + (size_t)et * 64 * EMBED;
    f32x4 z = {0.f, 0.f, 0.f, 0.f};
    f32x4 acc[2][4];
    for (int a = 0; a < 2; a++)
        for (int b = 0; b < 4; b++) acc[a][b] = z;

    bf16x8 afA[2], bfA[4], afB[2], bfB[4];
    auto loadA = [&](int kk) {
        for (int mt = 0; mt < 2; mt++)
            afA[mt] = *(const bf16x8*)(Ob + (size_t)(mt * 16 + m) * EMBED + kk + q8 * 8);
        for (int nt = 0; nt < 4; nt++)
            bfA[nt] = *(const bf16x8*)(Wb + (size_t)(nt * 16 + m) * EMBED + kk + q8 * 8);
    };
    auto loadB = [&](int kk) {
        for (int mt = 0; mt < 2; mt++)
            afB[mt] = *(const bf16x8*)(Ob + (size_t)(mt * 16 + m) * EMBED + kk + q8 * 8);
        for (int nt = 0; nt < 4; nt++)
            bfB[nt] = *(const bf16x8*)(Wb + (size_t)(nt * 16 + m) * EMBED + kk + q8 * 8);
    };
    loadA(0);
    loadB(32);
    for (int kk = 0; kk < EMBED; kk += 64) {
        for (int mt = 0; mt < 2; mt++)
            for (int nt = 0; nt < 4; nt++)
                acc[mt][nt] = MFMA16(afA[mt], bfA[nt], acc[mt][nt]);
        loadA((kk + 64) & (EMBED - 1));
        for (int mt = 0; mt < 2; mt++)
            for (int nt = 0; nt < 4; nt++)
                acc[mt][nt] = MFMA16(afB[mt], bfB[nt], acc[mt][nt]);
        loadB((kk + 96) & (EMBED - 1));
    }
    for (int nt = 0; nt < 4; nt++) {
        int col = et * 64 + nt * 16 + m;
        float bias = bo[col];
        for (int mt = 0; mt < 2; mt++)
            for (int j = 0; j < 4; j++) {
                int q = qb + mt * 16 + q8 * 4 + j;
                out[(size_t)q * EMBED + col] = acc[mt][nt][j] + bias;
            }
    }
}

extern "C" void kernel_launch(void* const* d_in, const int* in_sizes, int n_in,
                              void* d_out, int out_size, void* d_ws, size_t ws_size,
                              hipStream_t stream) {
    const float* values = (const float*)d_in[0];
    const float* keys   = (const float*)d_in[1];
    const float* query  = (const float*)d_in[2];
    const float* Wv     = (const float*)d_in[3];
    const float* Wk     = (const float*)d_in[4];
    const float* Wq     = (const float*)d_in[5];
    const float* Wo     = (const float*)d_in[6];
    const float* bo     = (const float*)d_in[7];
    float* out = (float*)d_out;

    char* ws = (char*)d_ws;
    bf16* Qp  = (bf16*)(ws);
    bf16* Kp  = (bf16*)(ws + (size_t)(16 << 20));
    bf16* Vt  = (bf16*)(ws + (size_t)(32 << 20));
    bf16* O   = (bf16*)(ws + (size_t)(48 << 20));
    bf16* Wob = (bf16*)(ws + (size_t)(64 << 20));
    bf16* Wqb = (bf16*)(ws + (size_t)(66 << 20));
    bf16* Wkb = (bf16*)(ws + (size_t)(66 << 20) + 8192);
    bf16* Wvb = (bf16*)(ws + (size_t)(66 << 20) + 16384);

    hipLaunchKernelGGL(convert_weights, dim3(518), dim3(256), 0, stream,
                       Wo, Wq, Wk, Wv, Wob, Wqb, Wkb, Wvb);
    hipLaunchKernelGGL(proj_kernel, dim3(2048), dim3(256), 0, stream,
                       values, keys, query, Wqb, Wkb, Wvb, Vt, Kp, Qp);
    hipLaunchKernelGGL(flash_kernel, dim3(64, 16), dim3(256), 0, stream, Qp, Kp, Vt, O);
    hipLaunchKernelGGL(outproj_kernel, dim3(16, 64), dim3(256), 0, stream, O, Wob, bo, out);
}